// Round 1
// baseline (1467.164 us; speedup 1.0000x reference)
//
#include <hip/hip_runtime.h>
#include <math.h>

#define NB 128
#define NA 1024
#define NK 10
#define EDIM 768
#define NS 4                   // splits of the NA dimension per batch
#define CHUNK (NA/NS)          // 256 tokens per block
#define WPB 4                  // waves per block
#define TPB 256
#define TPW (CHUNK/WPB)        // 64 tokens per wave
#define NG (TPW/4)             // 16 groups of 4 tokens
#define EPSV 1e-7f

// output layout (flat f32 in return order)
#define F_OFF   0
#define Z_OFF   196608
#define ZSA_OFF 1507328
#define ZSK_OFF 2818048
#define BA_OFF  4128768
#define BK_OFF  4259840

#define WS_META (NK*EDIM + EDIM)      // 8448: Upart[10][768], vmax[768]
#define WS_STRIDE (WS_META + 32)      // + m[10], l[10], mc[10], pad

// full-wave (64-lane) sum via DPP (VALU pipe, not LDS): row_shr 1,2,4,8 then row_bcast15/31
__device__ __forceinline__ float wave_sum(float v) {
#define DPPADD(ctrl) v += __int_as_float(__builtin_amdgcn_update_dpp(0, __float_as_int(v), ctrl, 0xf, 0xf, true))
  DPPADD(0x111); DPPADD(0x112); DPPADD(0x114); DPPADD(0x118);
  DPPADD(0x142); DPPADD(0x143);
#undef DPPADD
  return __int_as_float(__builtin_amdgcn_readlane(__float_as_int(v), 63));
}

// Pass 1: one block per (batch, a-split). Streams ans ONCE. Computes Z, Z_softmax_key^T,
// beta_ans, vmax partial, and online-softmax U partials (m,l,Uacc) + mc (for beta_key).
__global__ __launch_bounds__(TPB, 1) void kv_pass1(
    const float* __restrict__ ans, const float* __restrict__ mask_ans,
    const float* __restrict__ key, const float* __restrict__ mask_key,
    float* __restrict__ out, float* __restrict__ ws)
{
  const int s = blockIdx.x, b = blockIdx.y;
  const int tid = threadIdx.x;
  const int lane = tid & 63, wave = tid >> 6;

  __shared__ float key_s[NK][EDIM];     // masked key, 30 KiB
  __shared__ float red_u[NK][EDIM];     // U merge buffer, 30 KiB
  __shared__ float vred[WPB][EDIM];     // vmax merge, 12 KiB
  __shared__ float rnk_s[NK], mki_s[NK];
  __shared__ float shm[WPB][NK], shl[WPB][NK], shmc[WPB][NK];
  __shared__ float fm[NK];

  // stage masked key into LDS
  {
    const float* kb = key + (size_t)b*NK*EDIM;
    float* kd = &key_s[0][0];
    for (int i = tid*4; i < NK*EDIM; i += TPB*4) {
      float4 v = *(const float4*)(kb + i);
      float mk = mask_key[b*NK + (i / EDIM)];
      v.x*=mk; v.y*=mk; v.z*=mk; v.w*=mk;
      *(float4*)(kd + i) = v;
    }
  }
  __syncthreads();
  // key norms (on masked key, like reference) + mask_key_inf
  for (int k = wave; k < NK; k += WPB) {
    float ss = 0.f;
    for (int j = lane; j < EDIM; j += 64) { float t = key_s[k][j]; ss += t*t; }
    ss = wave_sum(ss);
    if (lane == 0) {
      rnk_s[k] = rsqrtf(fmaxf(ss, EPSV));                       // 1/norm_key
      mki_s[k] = (mask_key[b*NK + k] - 1.0f) * 10000.0f;        // 0 or -1e4
    }
  }
  __syncthreads();

  float Uacc[NK][12];           // e = (j>>2)*256 + lane*4 + (j&3)
  float vmax[12];
  float m[NK], l[NK], mc[NK];
#pragma unroll
  for (int k = 0; k < NK; ++k) {
    m[k] = -1e30f; l[k] = 0.f; mc[k] = -3e38f;
#pragma unroll
    for (int j = 0; j < 12; ++j) Uacc[k][j] = 0.f;
  }
#pragma unroll
  for (int j = 0; j < 12; ++j) vmax[j] = -3e38f;

  const float* ansb = ans + (size_t)b*NA*EDIM;
  const int abase = s*CHUNK + wave*TPW;

#pragma unroll 1
  for (int g = 0; g < NG; ++g) {
    const int a0 = abase + g*4;
    float av[4][12];
    float ma[4], mainf[4], rna[4], bfac[4];
    float zz[4][NK];

    // load 4 masked ans rows + norms
#pragma unroll
    for (int t = 0; t < 4; ++t) {
      const int a = a0 + t;
      const float mav = mask_ans[b*NA + a];
      ma[t] = mav; mainf[t] = (mav - 1.0f)*10000.0f;
      float ns = 0.f;
#pragma unroll
      for (int j = 0; j < 3; ++j) {
        float4 v = *(const float4*)(ansb + (size_t)a*EDIM + j*256 + lane*4);
        v.x*=mav; v.y*=mav; v.z*=mav; v.w*=mav;
        av[t][j*4+0]=v.x; av[t][j*4+1]=v.y; av[t][j*4+2]=v.z; av[t][j*4+3]=v.w;
        ns += v.x*v.x + v.y*v.y + v.z*v.z + v.w*v.w;
      }
      ns = wave_sum(ns);
      rna[t] = rsqrtf(fmaxf(ns, EPSV));                         // 1/norm_ans
    }

    // key sweep #1: dot products for 4 tokens (amortizes LDS reads)
#pragma unroll
    for (int k = 0; k < NK; ++k) {
      float kb0[12];
#pragma unroll
      for (int j = 0; j < 3; ++j) {
        float4 v = *(const float4*)(&key_s[k][j*256 + lane*4]);
        kb0[j*4+0]=v.x; kb0[j*4+1]=v.y; kb0[j*4+2]=v.z; kb0[j*4+3]=v.w;
      }
#pragma unroll
      for (int t = 0; t < 4; ++t) {
        float p = 0.f;
#pragma unroll
        for (int j = 0; j < 12; ++j) p += av[t][j]*kb0[j];
        zz[t][k] = p;
      }
    }
#pragma unroll
    for (int t = 0; t < 4; ++t)
#pragma unroll
      for (int k = 0; k < NK; ++k) zz[t][k] = wave_sum(zz[t][k]);

    float w[4][NK];
#pragma unroll
    for (int t = 0; t < 4; ++t) {
      const int a = a0 + t;
      {  // raw Z output: lanes 0..9 write k rows
        float zv = zz[t][0];
#pragma unroll
        for (int k = 1; k < NK; ++k) zv = (lane == k) ? zz[t][k] : zv;
        if (lane < NK) out[Z_OFF + ((size_t)b*NK + lane)*NA + a] = zv;
      }
      // softmax over k (Z^T + mask_key_inf)
      float mk = zz[t][0] + mki_s[0];
#pragma unroll
      for (int k = 1; k < NK; ++k) mk = fmaxf(mk, zz[t][k] + mki_s[k]);
      float sum = 0.f;
#pragma unroll
      for (int k = 0; k < NK; ++k) { float e = __expf(zz[t][k] + mki_s[k] - mk); w[t][k] = e; sum += e; }
      float rs = 1.0f / sum;
#pragma unroll
      for (int k = 0; k < NK; ++k) w[t][k] *= rs;
      {  // Z_softmax_key^T output
        float wv = w[t][0];
#pragma unroll
        for (int k = 1; k < NK; ++k) wv = (lane == k) ? w[t][k] : wv;
        if (lane < NK) out[ZSK_OFF + ((size_t)b*NK + lane)*NA + a] = wv;
      }
      // beta_ans = sigmoid(5*max_k(Zcos + mkinf)); mc[k] = max_a(Zcos + mainf) for beta_key
      float zc0 = zz[t][0]*rnk_s[0]*rna[t];
      float cb = zc0 + mki_s[0];
      mc[0] = fmaxf(mc[0], zc0 + mainf[t]);
#pragma unroll
      for (int k = 1; k < NK; ++k) {
        float zc = zz[t][k]*rnk_s[k]*rna[t];
        cb = fmaxf(cb, zc + mki_s[k]);
        mc[k] = fmaxf(mc[k], zc + mainf[t]);
      }
      float beta = 1.0f / (1.0f + __expf(-5.0f*cb));
      if (lane == 0) out[BA_OFF + (size_t)b*NA + a] = beta;
      bfac[t] = beta * ma[t];
      // online-softmax U accumulation (over a, per k) — this is what makes ans single-pass
#pragma unroll
      for (int k = 0; k < NK; ++k) {
        float sc = zz[t][k] + mainf[t];          // wave-uniform
        if (sc > m[k]) {
          float scale = __expf(m[k] - sc);
          m[k] = sc; l[k] *= scale;
#pragma unroll
          for (int j = 0; j < 12; ++j) Uacc[k][j] *= scale;
        }
        float p = __expf(sc - m[k]);
        l[k] += p;
#pragma unroll
        for (int j = 0; j < 12; ++j) Uacc[k][j] += p * av[t][j];
      }
    }

    // key sweep #2: V rows for 4 tokens, fold into running v-max
    float Vv[4][12];
#pragma unroll
    for (int t = 0; t < 4; ++t)
#pragma unroll
      for (int j = 0; j < 12; ++j) Vv[t][j] = 0.f;
#pragma unroll
    for (int k = 0; k < NK; ++k) {
      float kb0[12];
#pragma unroll
      for (int j = 0; j < 3; ++j) {
        float4 v = *(const float4*)(&key_s[k][j*256 + lane*4]);
        kb0[j*4+0]=v.x; kb0[j*4+1]=v.y; kb0[j*4+2]=v.z; kb0[j*4+3]=v.w;
      }
#pragma unroll
      for (int t = 0; t < 4; ++t)
#pragma unroll
        for (int j = 0; j < 12; ++j) Vv[t][j] += w[t][k]*kb0[j];
    }
#pragma unroll
    for (int t = 0; t < 4; ++t)
#pragma unroll
      for (int j = 0; j < 12; ++j) vmax[j] = fmaxf(vmax[j], Vv[t][j]*bfac[t]);
  }

  // ---- block combine across 4 waves ----
  if (lane == 0) {
#pragma unroll
    for (int k = 0; k < NK; ++k) { shm[wave][k]=m[k]; shl[wave][k]=l[k]; shmc[wave][k]=mc[k]; }
  }
#pragma unroll
  for (int j = 0; j < 12; ++j) vred[wave][(j>>2)*256 + lane*4 + (j&3)] = vmax[j];
  for (int i = tid; i < NK*EDIM; i += TPB) (&red_u[0][0])[i] = 0.f;
  __syncthreads();

  float* wsb = ws + (size_t)(b*NS + s)*WS_STRIDE;
  if (tid < NK) {
    const int k = tid;
    float M = shm[0][k];
#pragma unroll
    for (int w2 = 1; w2 < WPB; ++w2) M = fmaxf(M, shm[w2][k]);
    float L = 0.f, MC = shmc[0][k];
#pragma unroll
    for (int w2 = 0; w2 < WPB; ++w2) {
      L += shl[w2][k]*__expf(shm[w2][k]-M);
      MC = fmaxf(MC, shmc[w2][k]);
    }
    fm[k] = M;
    wsb[WS_META + k] = M;
    wsb[WS_META + NK + k] = L;
    wsb[WS_META + 2*NK + k] = MC;
  }
  __syncthreads();
#pragma unroll
  for (int k = 0; k < NK; ++k) {
    float fw = __expf(m[k] - fm[k]);
#pragma unroll
    for (int j = 0; j < 12; ++j)
      atomicAdd(&red_u[k][(j>>2)*256 + lane*4 + (j&3)], fw*Uacc[k][j]);
  }
  __syncthreads();
  for (int i = tid; i < NK*EDIM; i += TPB) wsb[i] = (&red_u[0][0])[i];
  for (int i = tid; i < EDIM; i += TPB)
    wsb[NK*EDIM + i] = fmaxf(fmaxf(vred[0][i], vred[1][i]), fmaxf(vred[2][i], vred[3][i]));
}

// Pass 2: per-batch combine of NS split partials; writes f (u|v), beta_key^T, Z_softmax_ans.
__global__ __launch_bounds__(256, 1) void kv_pass2(
    const float* __restrict__ mask_ans, const float* __restrict__ mask_key,
    float* __restrict__ out, const float* __restrict__ ws)
{
  const int b = blockIdx.x, tid = threadIdx.x;
  __shared__ float shM[NK], shRL[NK], shFac[NK], shF[NS][NK];
  if (tid < NK) {
    const int k = tid;
    const float* w0 = ws + (size_t)(b*NS)*WS_STRIDE + WS_META;
    float M = w0[k];
#pragma unroll
    for (int s2 = 1; s2 < NS; ++s2) M = fmaxf(M, w0[(size_t)s2*WS_STRIDE + k]);
    float L = 0.f, MC = -3e38f;
#pragma unroll
    for (int s2 = 0; s2 < NS; ++s2) {
      float ms = w0[(size_t)s2*WS_STRIDE + k];
      float f = __expf(ms - M);
      shF[s2][k] = f;
      L  += w0[(size_t)s2*WS_STRIDE + NK + k] * f;
      MC  = fmaxf(MC, w0[(size_t)s2*WS_STRIDE + 2*NK + k]);
    }
    float bk = 1.0f/(1.0f + __expf(-5.0f*MC));
    out[BK_OFF + b*NK + k] = bk;
    float rl = 1.0f / L;
    shM[k] = M; shRL[k] = rl;
    shFac[k] = rl * mask_key[b*NK + k] * bk;
  }
  __syncthreads();
  const float* wsb = ws + (size_t)(b*NS)*WS_STRIDE;
#pragma unroll 1
  for (int e = tid; e < EDIM; e += 256) {
    float u = -3e38f;
#pragma unroll
    for (int k = 0; k < NK; ++k) {
      float acc = 0.f;
#pragma unroll
      for (int s2 = 0; s2 < NS; ++s2) acc += shF[s2][k] * wsb[(size_t)s2*WS_STRIDE + k*EDIM + e];
      u = fmaxf(u, acc * shFac[k]);
    }
    out[(size_t)b*(2*EDIM) + e] = u;
    float v = wsb[NK*EDIM + e];
#pragma unroll
    for (int s2 = 1; s2 < NS; ++s2) v = fmaxf(v, wsb[(size_t)s2*WS_STRIDE + NK*EDIM + e]);
    out[(size_t)b*(2*EDIM) + EDIM + e] = v;
  }
  // Z_softmax_ans from raw Z written by pass 1
  for (int i = tid; i < NK*NA; i += 256) {
    const int a = i & (NA-1);
    const int k = i >> 10;
    float z = out[Z_OFF + (size_t)b*NK*NA + i];
    float mainf = (mask_ans[b*NA + a] - 1.0f) * 10000.0f;
    out[ZSA_OFF + (size_t)b*NK*NA + i] = __expf(z + mainf - shM[k]) * shRL[k];
  }
}

extern "C" void kernel_launch(void* const* d_in, const int* in_sizes, int n_in,
                              void* d_out, int out_size, void* d_ws, size_t ws_size,
                              hipStream_t stream) {
  const float* ans      = (const float*)d_in[0];
  const float* mask_ans = (const float*)d_in[1];
  const float* key      = (const float*)d_in[2];
  const float* mask_key = (const float*)d_in[3];
  float* out = (float*)d_out;
  float* ws  = (float*)d_ws;   // needs 128*4*8480*4 B ≈ 16.6 MiB

  dim3 g1(NS, NB);
  kv_pass1<<<g1, TPB, 0, stream>>>(ans, mask_ans, key, mask_key, out, ws);
  kv_pass2<<<NB, 256, 0, stream>>>(mask_ans, mask_key, out, ws);
}

// Round 3
// 1348.617 us; speedup vs baseline: 1.0879x; 1.0879x over previous
//
#include <hip/hip_runtime.h>
#include <math.h>

#define NB 128
#define NA 1024
#define NK 10
#define EDIM 768
#define NS 4                   // splits of NA per batch in pass 1
#define CHUNK (NA/NS)          // 256 tokens per block
#define WPB 4
#define TPB 256
#define TPW (CHUNK/WPB)        // 64 tokens per wave
#define EPSV 1e-7f

// output layout (flat f32, return order)
#define F_OFF   0
#define Z_OFF   196608
#define ZSA_OFF 1507328
#define ZSK_OFF 2818048
#define BA_OFF  4128768
#define BK_OFF  4259840

// workspace layout (floats)
#define WS_RNK 0                       // [B][NK]   1/norm_key
#define WS_RNA (WS_RNK + NB*NK)        // [B][NA]   1/norm_ans
#define WS_VP  (WS_RNA + NB*NA)        // [B][NS][EDIM] vmax partials
#define WS_FAC (WS_VP + NB*NS*EDIM)    // [B][NK]   mask_key*beta_key

// 64-lane sum via DPP (VALU pipe): row_shr 1,2,4,8 then row_bcast 15,31; result broadcast
__device__ __forceinline__ float wave_sum(float v) {
#define DPPADD(ctrl) v += __int_as_float(__builtin_amdgcn_update_dpp(0, __float_as_int(v), ctrl, 0xf, 0xf, true))
  DPPADD(0x111); DPPADD(0x112); DPPADD(0x114); DPPADD(0x118);
  DPPADD(0x142); DPPADD(0x143);
#undef DPPADD
  return __int_as_float(__builtin_amdgcn_readlane(__float_as_int(v), 63));
}
// 64-lane max via DPP (bound_ctrl=false: invalid lanes keep old → fmax(v,v) safe)
__device__ __forceinline__ float wave_max(float v) {
#define DPPMAX(ctrl) { float o_ = __int_as_float(__builtin_amdgcn_update_dpp(__float_as_int(v), __float_as_int(v), ctrl, 0xf, 0xf, false)); v = fmaxf(v, o_); }
  DPPMAX(0x111) DPPMAX(0x112) DPPMAX(0x114) DPPMAX(0x118)
  DPPMAX(0x142) DPPMAX(0x143)
#undef DPPMAX
  return __int_as_float(__builtin_amdgcn_readlane(__float_as_int(v), 63));
}

// Pass 1: one block per (split, batch). Streams ans ONCE.
// Emits: Z, ZSK^T, beta_ans (out); rnk, rna, vmax-partials (ws).
// No U state here — that's what spilled in round 1.
__global__ __launch_bounds__(TPB, 2) void kv_pass1(
    const float* __restrict__ ans, const float* __restrict__ mask_ans,
    const float* __restrict__ key, const float* __restrict__ mask_key,
    float* __restrict__ out, float* __restrict__ ws)
{
  const int s = blockIdx.x, b = blockIdx.y;
  const int tid = threadIdx.x;
  const int lane = tid & 63, wave = tid >> 6;

  __shared__ float key_s[NK][EDIM];    // 30 KiB masked key
  __shared__ float vred[WPB][EDIM];    // 12 KiB vmax merge
  __shared__ float rnk_s[NK], mki_s[NK];

  // stage masked key into LDS
  {
    const float* kb = key + (size_t)b*NK*EDIM;
    for (int i = tid*4; i < NK*EDIM; i += TPB*4) {
      float4 v = *(const float4*)(kb + i);
      float mk = mask_key[b*NK + (i / EDIM)];
      v.x*=mk; v.y*=mk; v.z*=mk; v.w*=mk;
      *(float4*)(&key_s[0][0] + i) = v;
    }
  }
  __syncthreads();
  for (int k = wave; k < NK; k += WPB) {
    float ssum = 0.f;
    for (int j = lane; j < EDIM; j += 64) { float t = key_s[k][j]; ssum += t*t; }
    ssum = wave_sum(ssum);
    if (lane == 0) {
      float r = rsqrtf(fmaxf(ssum, EPSV));
      rnk_s[k] = r;
      mki_s[k] = (mask_key[b*NK + k] - 1.0f) * 10000.0f;
      if (s == 0) ws[WS_RNK + b*NK + k] = r;
    }
  }
  __syncthreads();

  float vmax[12];
#pragma unroll
  for (int j = 0; j < 12; ++j) vmax[j] = -3e38f;

  const float* ansb = ans + (size_t)b*NA*EDIM;
  const int abase = s*CHUNK + wave*TPW;

#pragma unroll 1
  for (int g = 0; g < TPW/2; ++g) {          // 2 tokens per group
    const int a0 = abase + g*2;
    float av[2][12], rna2[2], ma2[2], bfac[2];
    float zz[2][NK], w[2][NK];

#pragma unroll
    for (int t = 0; t < 2; ++t) {
      const int a = a0 + t;
      const float mav = mask_ans[b*NA + a];
      ma2[t] = mav;
      float ns = 0.f;
#pragma unroll
      for (int j = 0; j < 3; ++j) {
        float4 v = *(const float4*)(ansb + (size_t)a*EDIM + j*256 + lane*4);
        v.x*=mav; v.y*=mav; v.z*=mav; v.w*=mav;
        av[t][j*4+0]=v.x; av[t][j*4+1]=v.y; av[t][j*4+2]=v.z; av[t][j*4+3]=v.w;
        ns += v.x*v.x + v.y*v.y + v.z*v.z + v.w*v.w;
      }
      ns = wave_sum(ns);
      rna2[t] = rsqrtf(fmaxf(ns, EPSV));
      if (lane == 0) ws[WS_RNA + b*NA + a] = rna2[t];
    }

    // dot sweep over keys (LDS reads amortized over 2 tokens)
#pragma unroll
    for (int k = 0; k < NK; ++k) {
      float kr[12];
#pragma unroll
      for (int j = 0; j < 3; ++j) {
        float4 v = *(const float4*)(&key_s[k][j*256 + lane*4]);
        kr[j*4+0]=v.x; kr[j*4+1]=v.y; kr[j*4+2]=v.z; kr[j*4+3]=v.w;
      }
      float p0 = 0.f, p1 = 0.f;
#pragma unroll
      for (int j = 0; j < 12; ++j) { p0 += av[0][j]*kr[j]; p1 += av[1][j]*kr[j]; }
      zz[0][k] = p0; zz[1][k] = p1;
    }
#pragma unroll
    for (int t = 0; t < 2; ++t)
#pragma unroll
      for (int k = 0; k < NK; ++k) zz[t][k] = wave_sum(zz[t][k]);

#pragma unroll
    for (int t = 0; t < 2; ++t) {
      const int a = a0 + t;
      {  // raw Z: lane k writes row k
        float zv = zz[t][0];
#pragma unroll
        for (int k = 1; k < NK; ++k) zv = (lane == k) ? zz[t][k] : zv;
        if (lane < NK) out[Z_OFF + ((size_t)(b*NK) + lane)*NA + a] = zv;
      }
      // softmax over k (key direction)
      float mk = -3e38f;
#pragma unroll
      for (int k = 0; k < NK; ++k) mk = fmaxf(mk, zz[t][k] + mki_s[k]);
      float sum = 0.f;
#pragma unroll
      for (int k = 0; k < NK; ++k) { float e = __expf(zz[t][k] + mki_s[k] - mk); w[t][k] = e; sum += e; }
      float rs = 1.0f / sum;
#pragma unroll
      for (int k = 0; k < NK; ++k) w[t][k] *= rs;
      {  // ZSK^T
        float wv = w[t][0];
#pragma unroll
        for (int k = 1; k < NK; ++k) wv = (lane == k) ? w[t][k] : wv;
        if (lane < NK) out[ZSK_OFF + ((size_t)(b*NK) + lane)*NA + a] = wv;
      }
      // beta_ans = sigmoid(5*max_k(Zcos + mki))
      float cb = -3e38f;
#pragma unroll
      for (int k = 0; k < NK; ++k) cb = fmaxf(cb, zz[t][k]*rnk_s[k]*rna2[t] + mki_s[k]);
      float beta = 1.0f / (1.0f + __expf(-5.0f*cb));
      if (lane == 0) out[BA_OFF + (size_t)b*NA + a] = beta;
      bfac[t] = beta * ma2[t];
    }

    // V sweep: V = softmax_key @ key, fold into running vmax
    float Vv[2][12];
#pragma unroll
    for (int t = 0; t < 2; ++t)
#pragma unroll
      for (int j = 0; j < 12; ++j) Vv[t][j] = 0.f;
#pragma unroll
    for (int k = 0; k < NK; ++k) {
      float kr[12];
#pragma unroll
      for (int j = 0; j < 3; ++j) {
        float4 v = *(const float4*)(&key_s[k][j*256 + lane*4]);
        kr[j*4+0]=v.x; kr[j*4+1]=v.y; kr[j*4+2]=v.z; kr[j*4+3]=v.w;
      }
#pragma unroll
      for (int t = 0; t < 2; ++t)
#pragma unroll
        for (int j = 0; j < 12; ++j) Vv[t][j] += w[t][k]*kr[j];
    }
#pragma unroll
    for (int t = 0; t < 2; ++t)
#pragma unroll
      for (int j = 0; j < 12; ++j) vmax[j] = fmaxf(vmax[j], Vv[t][j]*bfac[t]);
  }

  // merge 4 waves' vmax → ws partial
#pragma unroll
  for (int j = 0; j < 3; ++j)
    *(float4*)(&vred[wave][j*256 + lane*4]) =
      make_float4(vmax[j*4+0], vmax[j*4+1], vmax[j*4+2], vmax[j*4+3]);
  __syncthreads();
  for (int i = tid; i < EDIM; i += TPB)
    ws[WS_VP + ((size_t)(b*NS + s))*EDIM + i] =
      fmaxf(fmaxf(vred[0][i], vred[1][i]), fmaxf(vred[2][i], vred[3][i]));
}

// Pass 2: per-batch. From Z (in out, LLC-warm): softmax_ans stats M,L; beta_key; ZSA;
// v-half of f from vmax partials.
__global__ __launch_bounds__(256, 2) void kv_pass2(
    const float* __restrict__ mask_ans, const float* __restrict__ mask_key,
    float* __restrict__ out, float* __restrict__ ws)
{
  const int b = blockIdx.x, tid = threadIdx.x;
  const int lane = tid & 63, wave = tid >> 6;
  __shared__ float shM[NK], shRL[NK], shMC[NK];

  float mainf16[16], rna16[16];
#pragma unroll
  for (int i = 0; i < 16; ++i) {
    int a = i*64 + lane;
    mainf16[i] = (mask_ans[b*NA + a] - 1.0f) * 10000.0f;
    rna16[i]   = ws[WS_RNA + b*NA + a];
  }
  for (int k = wave; k < NK; k += 4) {
    float rnk = ws[WS_RNK + b*NK + k];
    float z16[16];
    float M = -3e38f, MC = -3e38f;
#pragma unroll
    for (int i = 0; i < 16; ++i) {
      float z = out[Z_OFF + ((size_t)(b*NK) + k)*NA + i*64 + lane];
      z16[i] = z;
      M  = fmaxf(M,  z + mainf16[i]);
      MC = fmaxf(MC, z*rnk*rna16[i] + mainf16[i]);
    }
    M = wave_max(M); MC = wave_max(MC);
    float L = 0.f;
#pragma unroll
    for (int i = 0; i < 16; ++i) L += __expf(z16[i] + mainf16[i] - M);
    L = wave_sum(L);
    if (lane == 0) { shM[k] = M; shRL[k] = 1.0f/L; shMC[k] = MC; }
  }
  __syncthreads();
  if (tid < NK) {
    float bk = 1.0f / (1.0f + __expf(-5.0f*shMC[tid]));
    out[BK_OFF + b*NK + tid] = bk;
    ws[WS_FAC + b*NK + tid] = bk * mask_key[b*NK + tid];
  }
  // ZSA (normalized)
  for (int i = tid; i < NK*NA; i += 256) {
    int k = i >> 10, a = i & (NA-1);
    float z = out[Z_OFF + (size_t)b*NK*NA + i];
    float mainf = (mask_ans[b*NA + a] - 1.0f) * 10000.0f;
    out[ZSA_OFF + (size_t)b*NK*NA + i] = __expf(z + mainf - shM[k]) * shRL[k];
  }
  // v-half of f
  {
    const float* vp = ws + WS_VP + (size_t)b*NS*EDIM;
    for (int e = tid; e < EDIM; e += 256) {
      float v = vp[e];
#pragma unroll
      for (int s2 = 1; s2 < NS; ++s2) v = fmaxf(v, vp[s2*EDIM + e]);
      out[(size_t)b*2*EDIM + EDIM + e] = v;
    }
  }
}

// Pass 3: u-half of f. U = ZSA @ ans (second streaming pass over ans),
// u = max_k(U * mask_key * beta_key). ZSA rows read via scalar (uniform) loads.
__global__ __launch_bounds__(192) void kv_pass3(
    const float* __restrict__ ans, float* out, const float* __restrict__ ws)
{
  const int es = blockIdx.x, b = blockIdx.y, tid = threadIdx.x;
  const int e = es*192 + tid;
  const float* zsa = out + ZSA_OFF + (size_t)b*NK*NA;   // uniform addresses → s_load
  const float* ap  = ans + (size_t)b*NA*EDIM + e;
  float acc[NK];
#pragma unroll
  for (int k = 0; k < NK; ++k) acc[k] = 0.f;

#pragma unroll 1
  for (int a0 = 0; a0 < NA; a0 += 8) {
    float av[8];
#pragma unroll
    for (int t = 0; t < 8; ++t) av[t] = ap[(size_t)(a0 + t)*EDIM];
#pragma unroll
    for (int k = 0; k < NK; ++k) {
#pragma unroll
      for (int t = 0; t < 8; ++t) acc[k] += zsa[k*NA + a0 + t] * av[t];
    }
  }
  float u = -3e38f;
  const float* fac = ws + WS_FAC + b*NK;
#pragma unroll
  for (int k = 0; k < NK; ++k) u = fmaxf(u, acc[k]*fac[k]);
  out[(size_t)b*2*EDIM + e] = u;
}

extern "C" void kernel_launch(void* const* d_in, const int* in_sizes, int n_in,
                              void* d_out, int out_size, void* d_ws, size_t ws_size,
                              hipStream_t stream) {
  const float* ans      = (const float*)d_in[0];
  const float* mask_ans = (const float*)d_in[1];
  const float* key      = (const float*)d_in[2];
  const float* mask_key = (const float*)d_in[3];
  float* out = (float*)d_out;
  float* ws  = (float*)d_ws;   // ~2.1 MB used

  dim3 g1(NS, NB);
  kv_pass1<<<g1, TPB, 0, stream>>>(ans, mask_ans, key, mask_key, out, ws);
  kv_pass2<<<NB, 256, 0, stream>>>(mask_ans, mask_key, out, ws);
  dim3 g3(4, NB);
  kv_pass3<<<g3, 192, 0, stream>>>(ans, out, ws);
}